// Round 2
// baseline (606.889 us; speedup 1.0000x reference)
//
#include <hip/hip_runtime.h>
#include <cmath>

// FAGCN: N=50000, E=1.6M, FEAT=512, HIDDEN=128, CLASS=40, 4 layers, eps=0.3
// R11: coef precompute — k_coef (per layer) computes tanh(al[s]+ar[d])*norm for
// every CSR slot + self-loop coef, so k_aggregate's hot loop is just
// csrc load -> hbf gather -> FMA (no tanh / al2 gather / shuffles on the
// critical path). R10 counters: aggregate VALUBusy 58%, HBM 40%, occ 60% —
// mixed VALU+latency bound from the 3-level dependent chain. coef/selfc alias
// the dead 'partial' buffer (no workspace growth). Rest unchanged from R10.

#define HIDDEN 128
#define FEAT 512
#define NCLASS 40
#define LDST 40    // GEMM LDS row stride in ushorts (80 B)
#define NB 256     // histogram chunks (= blocks)
#define PITCH 12544  // words per partial row: 4 nodes/word -> supports N<=50176
#define BM1 64     // k_gemm1 M-tile

typedef __attribute__((ext_vector_type(8))) short short8;
typedef __attribute__((ext_vector_type(4))) float f32x4;

__device__ __forceinline__ float bf_lo(unsigned u) { return __uint_as_float(u << 16); }
__device__ __forceinline__ float bf_hi(unsigned u) { return __uint_as_float(u & 0xffff0000u); }
__device__ __forceinline__ unsigned pack_bf16(float x, float y) {
    unsigned ux = __float_as_uint(x);
    unsigned uy = __float_as_uint(y);
    unsigned lx = (ux + 0x7fffu + ((ux >> 16) & 1u)) >> 16;
    unsigned hy = (uy + 0x7fffu + ((uy >> 16) & 1u)) & 0xffff0000u;
    return hy | lx;
}
__device__ __forceinline__ float fast_tanh(float x) {
    x = fminf(fmaxf(x, -15.f), 15.f);
    float e = __expf(2.f * x);
    return (e - 1.f) / (e + 1.f);
}

// ---------------- per-chunk LDS histogram (8-bit packed) + local rank ----------
__global__ __launch_bounds__(256) void k_hist(const int* __restrict__ ei, int E, int CE,
                                              unsigned* __restrict__ partial,
                                              ushort* __restrict__ lrank) {
    __shared__ unsigned lh[PITCH];
    const int b = blockIdx.x, tid = threadIdx.x;
    for (int w = tid; w < PITCH; w += 256) lh[w] = 0;
    __syncthreads();
    int e0 = b * CE, e1 = min(E, e0 + CE);
    for (int e = e0 + tid; e < e1; e += 256) {
        int dst = ei[E + e];
        int sh = (dst & 3) * 8;
        unsigned old = atomicAdd(&lh[dst >> 2], 1u << sh);
        lrank[e] = (ushort)((old >> sh) & 0xffu);
    }
    __syncthreads();
    unsigned* prow = partial + (size_t)b * PITCH;
    for (int w = tid; w < PITCH; w += 256) prow[w] = lh[w];
}

// ---------------- cross-chunk exclusive scan (in place) + degree unpack --------
__global__ void k_hscan(unsigned* __restrict__ partial, int* __restrict__ deg, int n) {
    int w = blockIdx.x * 256 + threadIdx.x;
    if (w >= PITCH) return;
    unsigned run = 0;
    size_t idx = w;
    for (int b = 0; b < NB; ++b, idx += PITCH) {
        unsigned v = partial[idx];
        partial[idx] = run;
        run += v;
    }
    int node = 4 * w;
    if (node < n)     deg[node]     = run & 0xffu;
    if (node + 1 < n) deg[node + 1] = (run >> 8) & 0xffu;
    if (node + 2 < n) deg[node + 2] = (run >> 16) & 0xffu;
    if (node + 3 < n) deg[node + 3] = run >> 24;
}

__global__ void k_dis(const int* __restrict__ deg, float* __restrict__ dis, int n) {
    int i = blockIdx.x * 256 + threadIdx.x;
    if (i < n) dis[i] = rsqrtf((float)(deg[i] + 1));
}

// ---------------- exclusive scan over node degrees (offs) ----------------
__global__ void k_scan1(const int* __restrict__ deg, int* __restrict__ offs,
                        int* __restrict__ part, int n) {
    __shared__ int s[256];
    int tid = threadIdx.x;
    int gid = blockIdx.x * 256 + tid;
    int v = (gid < n) ? deg[gid] : 0;
    s[tid] = v;
    __syncthreads();
    for (int off = 1; off < 256; off <<= 1) {
        int t = (tid >= off) ? s[tid - off] : 0;
        __syncthreads();
        s[tid] += t;
        __syncthreads();
    }
    if (gid < n) offs[gid] = s[tid] - v;
    if (tid == 255) part[blockIdx.x] = s[255];
}

__global__ void k_scan2(int* __restrict__ part, int nb) {
    __shared__ int s[256];
    int tid = threadIdx.x;
    int v = (tid < nb) ? part[tid] : 0;
    s[tid] = v;
    __syncthreads();
    for (int off = 1; off < 256; off <<= 1) {
        int t = (tid >= off) ? s[tid - off] : 0;
        __syncthreads();
        s[tid] += t;
        __syncthreads();
    }
    if (tid < nb) part[tid] = s[tid] - v;
}

__global__ void k_scan3(int* __restrict__ offs, const int* __restrict__ part, int n, int E) {
    int gid = blockIdx.x * 256 + threadIdx.x;
    if (gid < n) offs[gid] += part[blockIdx.x];
    if (gid == 0) offs[n] = E;
}

// ---------------- CSR fill: no atomics; chunk base row staged in LDS -----------
__global__ __launch_bounds__(256) void k_csr_fill(const int* __restrict__ ei, int E, int CE,
                                                  const int* __restrict__ offs,
                                                  const unsigned* __restrict__ partial,
                                                  const ushort* __restrict__ lrank,
                                                  int* __restrict__ csrc) {
    __shared__ unsigned lp[PITCH];
    const int b = blockIdx.x, tid = threadIdx.x;
    const unsigned* prow = partial + (size_t)b * PITCH;
    for (int w = tid; w < PITCH; w += 256) lp[w] = prow[w];
    __syncthreads();
    int e0 = b * CE, e1 = min(E, e0 + CE);
    for (int e = e0 + tid; e < e1; e += 256) {
        int dst = ei[E + e];
        int src = ei[e];
        unsigned wv = lp[dst >> 2];
        int base = (wv >> ((dst & 3) * 8)) & 0xffu;
        csrc[offs[dst] + base + (int)lrank[e]] = src;
    }
}

// ---------------- GEMM1: h = relu(x @ W1^T + b1), MFMA bf16 -------------------
__global__ __launch_bounds__(256) void k_gemm1(const float* __restrict__ x,
                                               const float* __restrict__ W1,
                                               const float* __restrict__ b1,
                                               float* __restrict__ h, int M) {
    __shared__ ushort As[BM1 * LDST];
    __shared__ ushort Bs[128 * LDST];
    const int tid = threadIdx.x;
    const int bm = blockIdx.x * BM1;
    const int wave = tid >> 6, lane = tid & 63;
    const int rh = (wave >> 1) * 32;   // wave row offset: 0 / 32
    const int ch = (wave & 1) * 64;    // wave col offset: 0 / 64
    const int sub = lane & 15, quad = lane >> 4;
    const int lrow = tid >> 3;         // 0..31
    const int lcol = (tid & 7) * 4;    // 0..28
    f32x4 acc[2][4] = {};
    float4 av[2], bv[4];
    // prologue: load K-tile 0 into registers
#pragma unroll
    for (int i = 0; i < 2; ++i) {
        int grow = bm + lrow + 32 * i;
        av[i] = (grow < M) ? *(const float4*)(x + (size_t)grow * FEAT + lcol)
                           : make_float4(0.f, 0.f, 0.f, 0.f);
    }
#pragma unroll
    for (int i = 0; i < 4; ++i)
        bv[i] = *(const float4*)(W1 + (size_t)(lrow + 32 * i) * FEAT + lcol);

    for (int k0 = 0; k0 < FEAT; k0 += 32) {
        // stage current tile regs -> LDS (bf16 pack)
#pragma unroll
        for (int i = 0; i < 2; ++i)
            *(uint2*)(As + (lrow + 32 * i) * LDST + lcol) =
                make_uint2(pack_bf16(av[i].x, av[i].y), pack_bf16(av[i].z, av[i].w));
#pragma unroll
        for (int i = 0; i < 4; ++i)
            *(uint2*)(Bs + (lrow + 32 * i) * LDST + lcol) =
                make_uint2(pack_bf16(bv[i].x, bv[i].y), pack_bf16(bv[i].z, bv[i].w));
        __syncthreads();
        // prefetch next K-tile into registers (overlaps ds_read + MFMA below)
        if (k0 + 32 < FEAT) {
            const int kn = k0 + 32;
#pragma unroll
            for (int i = 0; i < 2; ++i) {
                int grow = bm + lrow + 32 * i;
                av[i] = (grow < M) ? *(const float4*)(x + (size_t)grow * FEAT + kn + lcol)
                                   : make_float4(0.f, 0.f, 0.f, 0.f);
            }
#pragma unroll
            for (int i = 0; i < 4; ++i)
                bv[i] = *(const float4*)(W1 + (size_t)(lrow + 32 * i) * FEAT + kn + lcol);
        }
        short8 af[2], bfr[4];
#pragma unroll
        for (int t = 0; t < 2; ++t)
            af[t] = *(const short8*)(As + (rh + t * 16 + sub) * LDST + quad * 8);
#pragma unroll
        for (int u = 0; u < 4; ++u)
            bfr[u] = *(const short8*)(Bs + (ch + u * 16 + sub) * LDST + quad * 8);
#pragma unroll
        for (int t = 0; t < 2; ++t)
#pragma unroll
            for (int u = 0; u < 4; ++u)
                acc[t][u] = __builtin_amdgcn_mfma_f32_16x16x32_bf16(af[t], bfr[u], acc[t][u], 0, 0, 0);
        __syncthreads();
    }
    float b1v[4];
#pragma unroll
    for (int u = 0; u < 4; ++u) b1v[u] = b1[ch + u * 16 + sub];
#pragma unroll
    for (int t = 0; t < 2; ++t) {
#pragma unroll
        for (int u = 0; u < 4; ++u) {
            int col = ch + u * 16 + sub;
#pragma unroll
            for (int r2 = 0; r2 < 4; ++r2) {
                int grow = bm + rh + t * 16 + quad * 4 + r2;
                if (grow < M)
                    h[(size_t)grow * HIDDEN + col] = fmaxf(acc[t][u][r2] + b1v[u], 0.f);
            }
        }
    }
}

// ---------------- prep: bf16 pack + layer-0 dots -> {al,dis}, ar ----------------
__global__ void k_prep(const float* __restrict__ h, unsigned* __restrict__ hbf,
                       const float* __restrict__ attl, const float* __restrict__ attr,
                       const float* __restrict__ dis, float2* __restrict__ al2,
                       float* __restrict__ ar, int n) {
    int node = (blockIdx.x * blockDim.x + threadIdx.x) >> 6;
    int lane = threadIdx.x & 63;
    if (node >= n) return;
    float2 hv = ((const float2*)(h + (size_t)node * HIDDEN))[lane];
    hbf[(size_t)node * 64 + lane] = pack_bf16(hv.x, hv.y);
    float pl = hv.x * attl[2 * lane] + hv.y * attl[2 * lane + 1];
    float pr = hv.x * attr[2 * lane] + hv.y * attr[2 * lane + 1];
    for (int off = 32; off; off >>= 1) {
        pl += __shfl_down(pl, off);
        pr += __shfl_down(pr, off);
    }
    if (lane == 0) {
        al2[node] = make_float2(pl, dis[node]);
        ar[node] = pr;
    }
}

// ---------------- coef precompute: one wave per node, coalesced coef write ------
// coef[slot] = tanh(al[src]+ar[dst]) * dis[src] * dis[dst]; selfc per node.
// al2 table is 0.4 MB -> the random al2[src] gather is L2-resident.
__global__ void k_coef(const float2* __restrict__ al2, const float* __restrict__ ar,
                       const int* __restrict__ offs, const int* __restrict__ csrc,
                       float* __restrict__ coef, float* __restrict__ selfc, int n) {
    int node = (blockIdx.x * blockDim.x + threadIdx.x) >> 6;
    int lane = threadIdx.x & 63;
    if (node >= n) return;
    const float2 self = al2[node];
    const float arn = ar[node];
    const float disn = self.y;
    if (lane == 0) selfc[node] = fast_tanh(self.x + arn) * disn * disn;
    int e0 = offs[node], e1 = offs[node + 1];
    for (int e = e0 + lane; e < e1; e += 64) {
        int s = csrc[e];
        float2 ls = al2[s];
        coef[e] = fast_tanh(ls.x + arn) * ls.y * disn;
    }
}

// ---------------- aggregate: coef preloaded; hot loop = gather + FMA only ------
__global__ void k_aggregate(const unsigned* __restrict__ hbf, const float* __restrict__ raw,
                            const float* __restrict__ coef, const float* __restrict__ selfc,
                            const float* __restrict__ dis,
                            const int* __restrict__ offs, const int* __restrict__ csrc,
                            float* __restrict__ hout, unsigned* __restrict__ houtbf,
                            const float* __restrict__ attl_n, const float* __restrict__ attr_n,
                            float2* __restrict__ al2_o, float* __restrict__ ar_o, int n) {
    int node = (blockIdx.x * blockDim.x + threadIdx.x) >> 6;
    int lane = threadIdx.x & 63;
    if (node >= n) return;
    const int grp = lane >> 4;
    const int sub = lane & 15;
    float acc[8] = {0.f, 0.f, 0.f, 0.f, 0.f, 0.f, 0.f, 0.f};
    int e0 = offs[node], e1 = offs[node + 1];
    int e = e0;
    for (; e + 16 <= e1; e += 16) {
        // per-lane direct loads: 16 lanes of a grp hit the same address
        // (broadcast), all within one 64 B line per array.
        int sa = csrc[e + grp];
        int sb = csrc[e + 4 + grp];
        int sc = csrc[e + 8 + grp];
        int sd = csrc[e + 12 + grp];
        float ca = coef[e + grp];
        float cb = coef[e + 4 + grp];
        float cc = coef[e + 8 + grp];
        float cd = coef[e + 12 + grp];
        uint4 ra = *(const uint4*)(hbf + (size_t)sa * 64 + sub * 4);
        uint4 rb = *(const uint4*)(hbf + (size_t)sb * 64 + sub * 4);
        uint4 rc = *(const uint4*)(hbf + (size_t)sc * 64 + sub * 4);
        uint4 rd = *(const uint4*)(hbf + (size_t)sd * 64 + sub * 4);
        acc[0] += ca * bf_lo(ra.x); acc[1] += ca * bf_hi(ra.x);
        acc[2] += ca * bf_lo(ra.y); acc[3] += ca * bf_hi(ra.y);
        acc[4] += ca * bf_lo(ra.z); acc[5] += ca * bf_hi(ra.z);
        acc[6] += ca * bf_lo(ra.w); acc[7] += ca * bf_hi(ra.w);
        acc[0] += cb * bf_lo(rb.x); acc[1] += cb * bf_hi(rb.x);
        acc[2] += cb * bf_lo(rb.y); acc[3] += cb * bf_hi(rb.y);
        acc[4] += cb * bf_lo(rb.z); acc[5] += cb * bf_hi(rb.z);
        acc[6] += cb * bf_lo(rb.w); acc[7] += cb * bf_hi(rb.w);
        acc[0] += cc * bf_lo(rc.x); acc[1] += cc * bf_hi(rc.x);
        acc[2] += cc * bf_lo(rc.y); acc[3] += cc * bf_hi(rc.y);
        acc[4] += cc * bf_lo(rc.z); acc[5] += cc * bf_hi(rc.z);
        acc[6] += cc * bf_lo(rc.w); acc[7] += cc * bf_hi(rc.w);
        acc[0] += cd * bf_lo(rd.x); acc[1] += cd * bf_hi(rd.x);
        acc[2] += cd * bf_lo(rd.y); acc[3] += cd * bf_hi(rd.y);
        acc[4] += cd * bf_lo(rd.z); acc[5] += cd * bf_hi(rd.z);
        acc[6] += cd * bf_lo(rd.w); acc[7] += cd * bf_hi(rd.w);
    }
    for (; e + 4 <= e1; e += 4) {
        int sa = csrc[e + grp];
        float ca = coef[e + grp];
        uint4 ra = *(const uint4*)(hbf + (size_t)sa * 64 + sub * 4);
        acc[0] += ca * bf_lo(ra.x); acc[1] += ca * bf_hi(ra.x);
        acc[2] += ca * bf_lo(ra.y); acc[3] += ca * bf_hi(ra.y);
        acc[4] += ca * bf_lo(ra.z); acc[5] += ca * bf_hi(ra.z);
        acc[6] += ca * bf_lo(ra.w); acc[7] += ca * bf_hi(ra.w);
    }
#pragma unroll
    for (int j = 0; j < 8; ++j) {
        acc[j] += __shfl_xor(acc[j], 16);
        acc[j] += __shfl_xor(acc[j], 32);
    }
    for (; e < e1; ++e) {
        int s = csrc[e];
        float c = coef[e];
        uint4 r = *(const uint4*)(hbf + (size_t)s * 64 + sub * 4);
        acc[0] += c * bf_lo(r.x); acc[1] += c * bf_hi(r.x);
        acc[2] += c * bf_lo(r.y); acc[3] += c * bf_hi(r.y);
        acc[4] += c * bf_lo(r.z); acc[5] += c * bf_hi(r.z);
        acc[6] += c * bf_lo(r.w); acc[7] += c * bf_hi(r.w);
    }
    {
        float c = selfc[node];
        uint4 r = *(const uint4*)(hbf + (size_t)node * 64 + sub * 4);
        acc[0] += c * bf_lo(r.x); acc[1] += c * bf_hi(r.x);
        acc[2] += c * bf_lo(r.y); acc[3] += c * bf_hi(r.y);
        acc[4] += c * bf_lo(r.z); acc[5] += c * bf_hi(r.z);
        acc[6] += c * bf_lo(r.w); acc[7] += c * bf_hi(r.w);
    }
    float o[8];
    {
        float4 rv0 = *(const float4*)(raw + (size_t)node * HIDDEN + sub * 8);
        float4 rv1 = *(const float4*)(raw + (size_t)node * HIDDEN + sub * 8 + 4);
        o[0] = acc[0] + 0.3f * rv0.x; o[1] = acc[1] + 0.3f * rv0.y;
        o[2] = acc[2] + 0.3f * rv0.z; o[3] = acc[3] + 0.3f * rv0.w;
        o[4] = acc[4] + 0.3f * rv1.x; o[5] = acc[5] + 0.3f * rv1.y;
        o[6] = acc[6] + 0.3f * rv1.z; o[7] = acc[7] + 0.3f * rv1.w;
    }
    const float disn = dis[node];
    if (grp == 0) {
        *(float4*)(hout + (size_t)node * HIDDEN + sub * 8) = make_float4(o[0], o[1], o[2], o[3]);
        *(float4*)(hout + (size_t)node * HIDDEN + sub * 8 + 4) = make_float4(o[4], o[5], o[6], o[7]);
        if (houtbf) {
            uint4 pk = make_uint4(pack_bf16(o[0], o[1]), pack_bf16(o[2], o[3]),
                                  pack_bf16(o[4], o[5]), pack_bf16(o[6], o[7]));
            *(uint4*)(houtbf + (size_t)node * 64 + sub * 4) = pk;
        }
    }
    if (attl_n) {
        float4 a0 = *(const float4*)(attl_n + sub * 8);
        float4 a1 = *(const float4*)(attl_n + sub * 8 + 4);
        float4 c0 = *(const float4*)(attr_n + sub * 8);
        float4 c1 = *(const float4*)(attr_n + sub * 8 + 4);
        float pl = o[0] * a0.x + o[1] * a0.y + o[2] * a0.z + o[3] * a0.w +
                   o[4] * a1.x + o[5] * a1.y + o[6] * a1.z + o[7] * a1.w;
        float pr = o[0] * c0.x + o[1] * c0.y + o[2] * c0.z + o[3] * c0.w +
                   o[4] * c1.x + o[5] * c1.y + o[6] * c1.z + o[7] * c1.w;
        for (int off = 8; off; off >>= 1) {
            pl += __shfl_xor(pl, off);
            pr += __shfl_xor(pr, off);
        }
        if (lane == 0) {
            al2_o[node] = make_float2(pl, disn);
            ar_o[node] = pr;
        }
    }
}

// ---------------- output: log_softmax(h @ W2^T + b2) ---------------------------
__global__ __launch_bounds__(256) void k_out(const float* __restrict__ h,
                                             const float* __restrict__ W2,
                                             const float* __restrict__ b2,
                                             float* __restrict__ out, int n) {
    __shared__ float ws[NCLASS * HIDDEN];
    __shared__ float bs[NCLASS];
    const int tid = threadIdx.x;
    for (int i = tid; i < NCLASS * HIDDEN / 4; i += 256)
        ((float4*)ws)[i] = ((const float4*)W2)[i];
    if (tid < NCLASS) bs[tid] = b2[tid];
    __syncthreads();
    int node = blockIdx.x * 128 + (tid >> 1);
    const int half = tid & 1;
    const int c0 = half * 20;
    if (node >= n) return;
    const float* hr = h + (size_t)node * HIDDEN;
    float acc[20];
#pragma unroll
    for (int c = 0; c < 20; ++c) acc[c] = bs[c0 + c];
#pragma unroll
    for (int k0 = 0; k0 < HIDDEN; k0 += 16) {
        float4 h0 = *(const float4*)(hr + k0);
        float4 h1 = *(const float4*)(hr + k0 + 4);
        float4 h2v = *(const float4*)(hr + k0 + 8);
        float4 h3 = *(const float4*)(hr + k0 + 12);
#pragma unroll
        for (int c = 0; c < 20; ++c) {
            const float* w = ws + (c0 + c) * HIDDEN + k0;
            float4 w0 = *(const float4*)(w);
            float4 w1 = *(const float4*)(w + 4);
            float4 w2v = *(const float4*)(w + 8);
            float4 w3 = *(const float4*)(w + 12);
            acc[c] += h0.x * w0.x + h0.y * w0.y + h0.z * w0.z + h0.w * w0.w +
                      h1.x * w1.x + h1.y * w1.y + h1.z * w1.z + h1.w * w1.w +
                      h2v.x * w2v.x + h2v.y * w2v.y + h2v.z * w2v.z + h2v.w * w2v.w +
                      h3.x * w3.x + h3.y * w3.y + h3.z * w3.z + h3.w * w3.w;
        }
    }
    float m = -INFINITY;
#pragma unroll
    for (int c = 0; c < 20; ++c) m = fmaxf(m, acc[c]);
    m = fmaxf(m, __shfl_xor(m, 1));
    float ssum = 0.f;
#pragma unroll
    for (int c = 0; c < 20; ++c) ssum += expf(acc[c] - m);
    ssum += __shfl_xor(ssum, 1);
    float lse = m + logf(ssum);
    float* orow = out + (size_t)node * NCLASS + c0;
#pragma unroll
    for (int c = 0; c < 20; ++c) orow[c] = acc[c] - lse;
}

extern "C" void kernel_launch(void* const* d_in, const int* in_sizes, int n_in,
                              void* d_out, int out_size, void* d_ws, size_t ws_size,
                              hipStream_t stream) {
    const float* x    = (const float*)d_in[0];
    const int*   ei   = (const int*)d_in[1];
    const float* W1   = (const float*)d_in[2];
    const float* b1   = (const float*)d_in[3];
    const float* W2   = (const float*)d_in[4];
    const float* b2   = (const float*)d_in[5];
    const float* attl = (const float*)d_in[6];
    const float* attr = (const float*)d_in[7];
    const int N = in_sizes[0] / FEAT;
    const int E = in_sizes[1] / 2;
    float* out = (float*)d_out;

    char* p = (char*)d_ws;
    auto take = [&](size_t bytes) {
        void* q = (void*)p;
        p += (bytes + 255) & ~(size_t)255;
        return q;
    };
    float*    h0   = (float*)take((size_t)N * HIDDEN * 4);  // = raw
    float*    h1   = (float*)take((size_t)N * HIDDEN * 4);
    float*    h2   = (float*)take((size_t)N * HIDDEN * 4);
    unsigned* hb0  = (unsigned*)take((size_t)N * 64 * 4);
    unsigned* hb1  = (unsigned*)take((size_t)N * 64 * 4);
    int*      deg  = (int*)take((size_t)N * 4);
    float*    dis  = (float*)take((size_t)N * 4);
    int*      offs = (int*)take((size_t)(N + 1) * 4);
    unsigned* partial = (unsigned*)take((size_t)NB * PITCH * 4);
    ushort*   lrank   = (ushort*)take((size_t)E * 2);
    int*      csrc = (int*)take((size_t)E * 4);
    float2*   al2A = (float2*)take((size_t)N * 8);
    float2*   al2B = (float2*)take((size_t)N * 8);
    float*    arA  = (float*)take((size_t)N * 4);
    float*    arB  = (float*)take((size_t)N * 4);
    int*      part = (int*)take(1024);

    // coef/selfc alias the 'partial' buffer (12.8 MB; dead after CSR build).
    // E*4 + N*4 = 6.6 MB < NB*PITCH*4 = 12.8 MB.
    float*    coef  = (float*)partial;
    float*    selfc = coef + E;

    const int nbl = (N + 255) / 256;
    const int CE = (E + NB - 1) / NB;

    k_hist<<<NB, 256, 0, stream>>>(ei, E, CE, partial, lrank);
    k_hscan<<<(PITCH + 255) / 256, 256, 0, stream>>>(partial, deg, N);
    k_dis<<<nbl, 256, 0, stream>>>(deg, dis, N);
    k_scan1<<<nbl, 256, 0, stream>>>(deg, offs, part, N);
    k_scan2<<<1, 256, 0, stream>>>(part, nbl);
    k_scan3<<<nbl, 256, 0, stream>>>(offs, part, N, E);
    k_csr_fill<<<NB, 256, 0, stream>>>(ei, E, CE, offs, partial, lrank, csrc);

    k_gemm1<<<(N + BM1 - 1) / BM1, 256, 0, stream>>>(x, W1, b1, h0, N);
    k_prep<<<(N + 3) / 4, 256, 0, stream>>>(h0, hb0, attl, attr, dis, al2A, arA, N);

    float*    fout[4] = {h1, h2, h1, h2};
    unsigned* hbin = hb0, *hbout = hb1;
    float2*   alin = al2A, *alout = al2B;
    float*    arin = arA,  *arout = arB;
    for (int l = 0; l < 4; ++l) {
        const float* attl_n = (l < 3) ? (attl + (l + 1) * HIDDEN) : nullptr;
        const float* attr_n = (l < 3) ? (attr + (l + 1) * HIDDEN) : nullptr;
        unsigned* hbo = (l < 3) ? hbout : nullptr;
        k_coef<<<(N + 3) / 4, 256, 0, stream>>>(alin, arin, offs, csrc, coef, selfc, N);
        k_aggregate<<<(N + 3) / 4, 256, 0, stream>>>(hbin, h0, coef, selfc, dis, offs, csrc,
                                                     fout[l], hbo, attl_n, attr_n,
                                                     alout, arout, N);
        unsigned* tb = hbin; hbin = hbout; hbout = tb;
        float2* ta = alin; alin = alout; alout = ta;
        float* tr = arin; arin = arout; arout = tr;
    }

    k_out<<<(N + 127) / 128, 256, 0, stream>>>(h2, W2, b2, out, N);
}

// Round 3
// 584.047 us; speedup vs baseline: 1.0391x; 1.0391x over previous
//
#include <hip/hip_runtime.h>
#include <cmath>

// FAGCN: N=50000, E=1.6M, FEAT=512, HIDDEN=128, CLASS=40, 4 layers, eps=0.3
// R12: k_out restructured — 8 lanes/node (5 classes each, classes strided by 8),
// grid 1563 blocks, acc[5], ws padded to stride 132 floats (4-bank shift/row ->
// conflict-free ds_read_b128), softmax via shfl_xor(1,2,4),
// __launch_bounds__(256,4) to pin regalloc. R11 counters: k_out 99.6us,
// VGPR 168 (co-compile perturbation), occ 10% (1.5 blocks/CU), VALU 9%,
// 5.5M LDS bank conflicts. k_coef/k_aggregate unchanged from R11 so next
// round's counters attribute the aggregate delta cleanly.

#define HIDDEN 128
#define FEAT 512
#define NCLASS 40
#define LDST 40    // GEMM LDS row stride in ushorts (80 B)
#define LDSW 132   // k_out ws row stride in floats (528 B -> 4-bank shift/row)
#define NB 256     // histogram chunks (= blocks)
#define PITCH 12544  // words per partial row: 4 nodes/word -> supports N<=50176
#define BM1 64     // k_gemm1 M-tile

typedef __attribute__((ext_vector_type(8))) short short8;
typedef __attribute__((ext_vector_type(4))) float f32x4;

__device__ __forceinline__ float bf_lo(unsigned u) { return __uint_as_float(u << 16); }
__device__ __forceinline__ float bf_hi(unsigned u) { return __uint_as_float(u & 0xffff0000u); }
__device__ __forceinline__ unsigned pack_bf16(float x, float y) {
    unsigned ux = __float_as_uint(x);
    unsigned uy = __float_as_uint(y);
    unsigned lx = (ux + 0x7fffu + ((ux >> 16) & 1u)) >> 16;
    unsigned hy = (uy + 0x7fffu + ((uy >> 16) & 1u)) & 0xffff0000u;
    return hy | lx;
}
__device__ __forceinline__ float fast_tanh(float x) {
    x = fminf(fmaxf(x, -15.f), 15.f);
    float e = __expf(2.f * x);
    return (e - 1.f) / (e + 1.f);
}

// ---------------- per-chunk LDS histogram (8-bit packed) + local rank ----------
__global__ __launch_bounds__(256) void k_hist(const int* __restrict__ ei, int E, int CE,
                                              unsigned* __restrict__ partial,
                                              ushort* __restrict__ lrank) {
    __shared__ unsigned lh[PITCH];
    const int b = blockIdx.x, tid = threadIdx.x;
    for (int w = tid; w < PITCH; w += 256) lh[w] = 0;
    __syncthreads();
    int e0 = b * CE, e1 = min(E, e0 + CE);
    for (int e = e0 + tid; e < e1; e += 256) {
        int dst = ei[E + e];
        int sh = (dst & 3) * 8;
        unsigned old = atomicAdd(&lh[dst >> 2], 1u << sh);
        lrank[e] = (ushort)((old >> sh) & 0xffu);
    }
    __syncthreads();
    unsigned* prow = partial + (size_t)b * PITCH;
    for (int w = tid; w < PITCH; w += 256) prow[w] = lh[w];
}

// ---------------- cross-chunk exclusive scan (in place) + degree unpack --------
__global__ void k_hscan(unsigned* __restrict__ partial, int* __restrict__ deg, int n) {
    int w = blockIdx.x * 256 + threadIdx.x;
    if (w >= PITCH) return;
    unsigned run = 0;
    size_t idx = w;
    for (int b = 0; b < NB; ++b, idx += PITCH) {
        unsigned v = partial[idx];
        partial[idx] = run;
        run += v;
    }
    int node = 4 * w;
    if (node < n)     deg[node]     = run & 0xffu;
    if (node + 1 < n) deg[node + 1] = (run >> 8) & 0xffu;
    if (node + 2 < n) deg[node + 2] = (run >> 16) & 0xffu;
    if (node + 3 < n) deg[node + 3] = run >> 24;
}

__global__ void k_dis(const int* __restrict__ deg, float* __restrict__ dis, int n) {
    int i = blockIdx.x * 256 + threadIdx.x;
    if (i < n) dis[i] = rsqrtf((float)(deg[i] + 1));
}

// ---------------- exclusive scan over node degrees (offs) ----------------
__global__ void k_scan1(const int* __restrict__ deg, int* __restrict__ offs,
                        int* __restrict__ part, int n) {
    __shared__ int s[256];
    int tid = threadIdx.x;
    int gid = blockIdx.x * 256 + tid;
    int v = (gid < n) ? deg[gid] : 0;
    s[tid] = v;
    __syncthreads();
    for (int off = 1; off < 256; off <<= 1) {
        int t = (tid >= off) ? s[tid - off] : 0;
        __syncthreads();
        s[tid] += t;
        __syncthreads();
    }
    if (gid < n) offs[gid] = s[tid] - v;
    if (tid == 255) part[blockIdx.x] = s[255];
}

__global__ void k_scan2(int* __restrict__ part, int nb) {
    __shared__ int s[256];
    int tid = threadIdx.x;
    int v = (tid < nb) ? part[tid] : 0;
    s[tid] = v;
    __syncthreads();
    for (int off = 1; off < 256; off <<= 1) {
        int t = (tid >= off) ? s[tid - off] : 0;
        __syncthreads();
        s[tid] += t;
        __syncthreads();
    }
    if (tid < nb) part[tid] = s[tid] - v;
}

__global__ void k_scan3(int* __restrict__ offs, const int* __restrict__ part, int n, int E) {
    int gid = blockIdx.x * 256 + threadIdx.x;
    if (gid < n) offs[gid] += part[blockIdx.x];
    if (gid == 0) offs[n] = E;
}

// ---------------- CSR fill: no atomics; chunk base row staged in LDS -----------
__global__ __launch_bounds__(256) void k_csr_fill(const int* __restrict__ ei, int E, int CE,
                                                  const int* __restrict__ offs,
                                                  const unsigned* __restrict__ partial,
                                                  const ushort* __restrict__ lrank,
                                                  int* __restrict__ csrc) {
    __shared__ unsigned lp[PITCH];
    const int b = blockIdx.x, tid = threadIdx.x;
    const unsigned* prow = partial + (size_t)b * PITCH;
    for (int w = tid; w < PITCH; w += 256) lp[w] = prow[w];
    __syncthreads();
    int e0 = b * CE, e1 = min(E, e0 + CE);
    for (int e = e0 + tid; e < e1; e += 256) {
        int dst = ei[E + e];
        int src = ei[e];
        unsigned wv = lp[dst >> 2];
        int base = (wv >> ((dst & 3) * 8)) & 0xffu;
        csrc[offs[dst] + base + (int)lrank[e]] = src;
    }
}

// ---------------- GEMM1: h = relu(x @ W1^T + b1), MFMA bf16 -------------------
__global__ __launch_bounds__(256) void k_gemm1(const float* __restrict__ x,
                                               const float* __restrict__ W1,
                                               const float* __restrict__ b1,
                                               float* __restrict__ h, int M) {
    __shared__ ushort As[BM1 * LDST];
    __shared__ ushort Bs[128 * LDST];
    const int tid = threadIdx.x;
    const int bm = blockIdx.x * BM1;
    const int wave = tid >> 6, lane = tid & 63;
    const int rh = (wave >> 1) * 32;   // wave row offset: 0 / 32
    const int ch = (wave & 1) * 64;    // wave col offset: 0 / 64
    const int sub = lane & 15, quad = lane >> 4;
    const int lrow = tid >> 3;         // 0..31
    const int lcol = (tid & 7) * 4;    // 0..28
    f32x4 acc[2][4] = {};
    float4 av[2], bv[4];
    // prologue: load K-tile 0 into registers
#pragma unroll
    for (int i = 0; i < 2; ++i) {
        int grow = bm + lrow + 32 * i;
        av[i] = (grow < M) ? *(const float4*)(x + (size_t)grow * FEAT + lcol)
                           : make_float4(0.f, 0.f, 0.f, 0.f);
    }
#pragma unroll
    for (int i = 0; i < 4; ++i)
        bv[i] = *(const float4*)(W1 + (size_t)(lrow + 32 * i) * FEAT + lcol);

    for (int k0 = 0; k0 < FEAT; k0 += 32) {
        // stage current tile regs -> LDS (bf16 pack)
#pragma unroll
        for (int i = 0; i < 2; ++i)
            *(uint2*)(As + (lrow + 32 * i) * LDST + lcol) =
                make_uint2(pack_bf16(av[i].x, av[i].y), pack_bf16(av[i].z, av[i].w));
#pragma unroll
        for (int i = 0; i < 4; ++i)
            *(uint2*)(Bs + (lrow + 32 * i) * LDST + lcol) =
                make_uint2(pack_bf16(bv[i].x, bv[i].y), pack_bf16(bv[i].z, bv[i].w));
        __syncthreads();
        // prefetch next K-tile into registers (overlaps ds_read + MFMA below)
        if (k0 + 32 < FEAT) {
            const int kn = k0 + 32;
#pragma unroll
            for (int i = 0; i < 2; ++i) {
                int grow = bm + lrow + 32 * i;
                av[i] = (grow < M) ? *(const float4*)(x + (size_t)grow * FEAT + kn + lcol)
                                   : make_float4(0.f, 0.f, 0.f, 0.f);
            }
#pragma unroll
            for (int i = 0; i < 4; ++i)
                bv[i] = *(const float4*)(W1 + (size_t)(lrow + 32 * i) * FEAT + kn + lcol);
        }
        short8 af[2], bfr[4];
#pragma unroll
        for (int t = 0; t < 2; ++t)
            af[t] = *(const short8*)(As + (rh + t * 16 + sub) * LDST + quad * 8);
#pragma unroll
        for (int u = 0; u < 4; ++u)
            bfr[u] = *(const short8*)(Bs + (ch + u * 16 + sub) * LDST + quad * 8);
#pragma unroll
        for (int t = 0; t < 2; ++t)
#pragma unroll
            for (int u = 0; u < 4; ++u)
                acc[t][u] = __builtin_amdgcn_mfma_f32_16x16x32_bf16(af[t], bfr[u], acc[t][u], 0, 0, 0);
        __syncthreads();
    }
    float b1v[4];
#pragma unroll
    for (int u = 0; u < 4; ++u) b1v[u] = b1[ch + u * 16 + sub];
#pragma unroll
    for (int t = 0; t < 2; ++t) {
#pragma unroll
        for (int u = 0; u < 4; ++u) {
            int col = ch + u * 16 + sub;
#pragma unroll
            for (int r2 = 0; r2 < 4; ++r2) {
                int grow = bm + rh + t * 16 + quad * 4 + r2;
                if (grow < M)
                    h[(size_t)grow * HIDDEN + col] = fmaxf(acc[t][u][r2] + b1v[u], 0.f);
            }
        }
    }
}

// ---------------- prep: bf16 pack + layer-0 dots -> {al,dis}, ar ----------------
__global__ void k_prep(const float* __restrict__ h, unsigned* __restrict__ hbf,
                       const float* __restrict__ attl, const float* __restrict__ attr,
                       const float* __restrict__ dis, float2* __restrict__ al2,
                       float* __restrict__ ar, int n) {
    int node = (blockIdx.x * blockDim.x + threadIdx.x) >> 6;
    int lane = threadIdx.x & 63;
    if (node >= n) return;
    float2 hv = ((const float2*)(h + (size_t)node * HIDDEN))[lane];
    hbf[(size_t)node * 64 + lane] = pack_bf16(hv.x, hv.y);
    float pl = hv.x * attl[2 * lane] + hv.y * attl[2 * lane + 1];
    float pr = hv.x * attr[2 * lane] + hv.y * attr[2 * lane + 1];
    for (int off = 32; off; off >>= 1) {
        pl += __shfl_down(pl, off);
        pr += __shfl_down(pr, off);
    }
    if (lane == 0) {
        al2[node] = make_float2(pl, dis[node]);
        ar[node] = pr;
    }
}

// ---------------- coef precompute: one wave per node, coalesced coef write ------
__global__ void k_coef(const float2* __restrict__ al2, const float* __restrict__ ar,
                       const int* __restrict__ offs, const int* __restrict__ csrc,
                       float* __restrict__ coef, float* __restrict__ selfc, int n) {
    int node = (blockIdx.x * blockDim.x + threadIdx.x) >> 6;
    int lane = threadIdx.x & 63;
    if (node >= n) return;
    const float2 self = al2[node];
    const float arn = ar[node];
    const float disn = self.y;
    if (lane == 0) selfc[node] = fast_tanh(self.x + arn) * disn * disn;
    int e0 = offs[node], e1 = offs[node + 1];
    for (int e = e0 + lane; e < e1; e += 64) {
        int s = csrc[e];
        float2 ls = al2[s];
        coef[e] = fast_tanh(ls.x + arn) * ls.y * disn;
    }
}

// ---------------- aggregate: coef preloaded; hot loop = gather + FMA only ------
__global__ void k_aggregate(const unsigned* __restrict__ hbf, const float* __restrict__ raw,
                            const float* __restrict__ coef, const float* __restrict__ selfc,
                            const float* __restrict__ dis,
                            const int* __restrict__ offs, const int* __restrict__ csrc,
                            float* __restrict__ hout, unsigned* __restrict__ houtbf,
                            const float* __restrict__ attl_n, const float* __restrict__ attr_n,
                            float2* __restrict__ al2_o, float* __restrict__ ar_o, int n) {
    int node = (blockIdx.x * blockDim.x + threadIdx.x) >> 6;
    int lane = threadIdx.x & 63;
    if (node >= n) return;
    const int grp = lane >> 4;
    const int sub = lane & 15;
    float acc[8] = {0.f, 0.f, 0.f, 0.f, 0.f, 0.f, 0.f, 0.f};
    int e0 = offs[node], e1 = offs[node + 1];
    int e = e0;
    for (; e + 16 <= e1; e += 16) {
        int sa = csrc[e + grp];
        int sb = csrc[e + 4 + grp];
        int sc = csrc[e + 8 + grp];
        int sd = csrc[e + 12 + grp];
        float ca = coef[e + grp];
        float cb = coef[e + 4 + grp];
        float cc = coef[e + 8 + grp];
        float cd = coef[e + 12 + grp];
        uint4 ra = *(const uint4*)(hbf + (size_t)sa * 64 + sub * 4);
        uint4 rb = *(const uint4*)(hbf + (size_t)sb * 64 + sub * 4);
        uint4 rc = *(const uint4*)(hbf + (size_t)sc * 64 + sub * 4);
        uint4 rd = *(const uint4*)(hbf + (size_t)sd * 64 + sub * 4);
        acc[0] += ca * bf_lo(ra.x); acc[1] += ca * bf_hi(ra.x);
        acc[2] += ca * bf_lo(ra.y); acc[3] += ca * bf_hi(ra.y);
        acc[4] += ca * bf_lo(ra.z); acc[5] += ca * bf_hi(ra.z);
        acc[6] += ca * bf_lo(ra.w); acc[7] += ca * bf_hi(ra.w);
        acc[0] += cb * bf_lo(rb.x); acc[1] += cb * bf_hi(rb.x);
        acc[2] += cb * bf_lo(rb.y); acc[3] += cb * bf_hi(rb.y);
        acc[4] += cb * bf_lo(rb.z); acc[5] += cb * bf_hi(rb.z);
        acc[6] += cb * bf_lo(rb.w); acc[7] += cb * bf_hi(rb.w);
        acc[0] += cc * bf_lo(rc.x); acc[1] += cc * bf_hi(rc.x);
        acc[2] += cc * bf_lo(rc.y); acc[3] += cc * bf_hi(rc.y);
        acc[4] += cc * bf_lo(rc.z); acc[5] += cc * bf_hi(rc.z);
        acc[6] += cc * bf_lo(rc.w); acc[7] += cc * bf_hi(rc.w);
        acc[0] += cd * bf_lo(rd.x); acc[1] += cd * bf_hi(rd.x);
        acc[2] += cd * bf_lo(rd.y); acc[3] += cd * bf_hi(rd.y);
        acc[4] += cd * bf_lo(rd.z); acc[5] += cd * bf_hi(rd.z);
        acc[6] += cd * bf_lo(rd.w); acc[7] += cd * bf_hi(rd.w);
    }
    for (; e + 4 <= e1; e += 4) {
        int sa = csrc[e + grp];
        float ca = coef[e + grp];
        uint4 ra = *(const uint4*)(hbf + (size_t)sa * 64 + sub * 4);
        acc[0] += ca * bf_lo(ra.x); acc[1] += ca * bf_hi(ra.x);
        acc[2] += ca * bf_lo(ra.y); acc[3] += ca * bf_hi(ra.y);
        acc[4] += ca * bf_lo(ra.z); acc[5] += ca * bf_hi(ra.z);
        acc[6] += ca * bf_lo(ra.w); acc[7] += ca * bf_hi(ra.w);
    }
#pragma unroll
    for (int j = 0; j < 8; ++j) {
        acc[j] += __shfl_xor(acc[j], 16);
        acc[j] += __shfl_xor(acc[j], 32);
    }
    for (; e < e1; ++e) {
        int s = csrc[e];
        float c = coef[e];
        uint4 r = *(const uint4*)(hbf + (size_t)s * 64 + sub * 4);
        acc[0] += c * bf_lo(r.x); acc[1] += c * bf_hi(r.x);
        acc[2] += c * bf_lo(r.y); acc[3] += c * bf_hi(r.y);
        acc[4] += c * bf_lo(r.z); acc[5] += c * bf_hi(r.z);
        acc[6] += c * bf_lo(r.w); acc[7] += c * bf_hi(r.w);
    }
    {
        float c = selfc[node];
        uint4 r = *(const uint4*)(hbf + (size_t)node * 64 + sub * 4);
        acc[0] += c * bf_lo(r.x); acc[1] += c * bf_hi(r.x);
        acc[2] += c * bf_lo(r.y); acc[3] += c * bf_hi(r.y);
        acc[4] += c * bf_lo(r.z); acc[5] += c * bf_hi(r.z);
        acc[6] += c * bf_lo(r.w); acc[7] += c * bf_hi(r.w);
    }
    float o[8];
    {
        float4 rv0 = *(const float4*)(raw + (size_t)node * HIDDEN + sub * 8);
        float4 rv1 = *(const float4*)(raw + (size_t)node * HIDDEN + sub * 8 + 4);
        o[0] = acc[0] + 0.3f * rv0.x; o[1] = acc[1] + 0.3f * rv0.y;
        o[2] = acc[2] + 0.3f * rv0.z; o[3] = acc[3] + 0.3f * rv0.w;
        o[4] = acc[4] + 0.3f * rv1.x; o[5] = acc[5] + 0.3f * rv1.y;
        o[6] = acc[6] + 0.3f * rv1.z; o[7] = acc[7] + 0.3f * rv1.w;
    }
    const float disn = dis[node];
    if (grp == 0) {
        *(float4*)(hout + (size_t)node * HIDDEN + sub * 8) = make_float4(o[0], o[1], o[2], o[3]);
        *(float4*)(hout + (size_t)node * HIDDEN + sub * 8 + 4) = make_float4(o[4], o[5], o[6], o[7]);
        if (houtbf) {
            uint4 pk = make_uint4(pack_bf16(o[0], o[1]), pack_bf16(o[2], o[3]),
                                  pack_bf16(o[4], o[5]), pack_bf16(o[6], o[7]));
            *(uint4*)(houtbf + (size_t)node * 64 + sub * 4) = pk;
        }
    }
    if (attl_n) {
        float4 a0 = *(const float4*)(attl_n + sub * 8);
        float4 a1 = *(const float4*)(attl_n + sub * 8 + 4);
        float4 c0 = *(const float4*)(attr_n + sub * 8);
        float4 c1 = *(const float4*)(attr_n + sub * 8 + 4);
        float pl = o[0] * a0.x + o[1] * a0.y + o[2] * a0.z + o[3] * a0.w +
                   o[4] * a1.x + o[5] * a1.y + o[6] * a1.z + o[7] * a1.w;
        float pr = o[0] * c0.x + o[1] * c0.y + o[2] * c0.z + o[3] * c0.w +
                   o[4] * c1.x + o[5] * c1.y + o[6] * c1.z + o[7] * c1.w;
        for (int off = 8; off; off >>= 1) {
            pl += __shfl_xor(pl, off);
            pr += __shfl_xor(pr, off);
        }
        if (lane == 0) {
            al2_o[node] = make_float2(pl, disn);
            ar_o[node] = pr;
        }
    }
}

// ---------------- output: log_softmax(h @ W2^T + b2) ---------------------------
// 8 lanes/node; lane ol=tid&7 computes classes {ol, ol+8, ..., ol+32} (acc[5]).
// ws padded to LDSW=132 floats/row: row r starts at bank 4r mod 32, so the 8
// lanes of a group cover all 32 banks -> conflict-free ds_read_b128.
// Softmax combined over the 8-lane group via shfl_xor(1,2,4).
__global__ __launch_bounds__(256, 4) void k_out(const float* __restrict__ h,
                                                const float* __restrict__ W2,
                                                const float* __restrict__ b2,
                                                float* __restrict__ out, int n) {
    __shared__ float ws[NCLASS * LDSW];
    __shared__ float bs[NCLASS];
    const int tid = threadIdx.x;
    for (int i = tid; i < NCLASS * (HIDDEN / 4); i += 256) {
        int r = i >> 5;          // row (class), 32 float4 per row
        int c4 = i & 31;         // float4 index within row
        *(float4*)(ws + r * LDSW + c4 * 4) = ((const float4*)W2)[i];
    }
    if (tid < NCLASS) bs[tid] = b2[tid];
    __syncthreads();
    int node = blockIdx.x * 32 + (tid >> 3);
    const int ol = tid & 7;
    if (node >= n) return;
    const float* hr = h + (size_t)node * HIDDEN;
    float acc[5];
#pragma unroll
    for (int c = 0; c < 5; ++c) acc[c] = bs[ol + 8 * c];
#pragma unroll
    for (int k0 = 0; k0 < HIDDEN; k0 += 16) {
        float4 h0 = *(const float4*)(hr + k0);
        float4 h1 = *(const float4*)(hr + k0 + 4);
        float4 h2v = *(const float4*)(hr + k0 + 8);
        float4 h3 = *(const float4*)(hr + k0 + 12);
#pragma unroll
        for (int c = 0; c < 5; ++c) {
            const float* w = ws + (ol + 8 * c) * LDSW + k0;
            float4 w0 = *(const float4*)(w);
            float4 w1 = *(const float4*)(w + 4);
            float4 w2v = *(const float4*)(w + 8);
            float4 w3 = *(const float4*)(w + 12);
            acc[c] += h0.x * w0.x + h0.y * w0.y + h0.z * w0.z + h0.w * w0.w +
                      h1.x * w1.x + h1.y * w1.y + h1.z * w1.z + h1.w * w1.w +
                      h2v.x * w2v.x + h2v.y * w2v.y + h2v.z * w2v.z + h2v.w * w2v.w +
                      h3.x * w3.x + h3.y * w3.y + h3.z * w3.z + h3.w * w3.w;
        }
    }
    float m = acc[0];
#pragma unroll
    for (int c = 1; c < 5; ++c) m = fmaxf(m, acc[c]);
    m = fmaxf(m, __shfl_xor(m, 1));
    m = fmaxf(m, __shfl_xor(m, 2));
    m = fmaxf(m, __shfl_xor(m, 4));
    float ssum = 0.f;
#pragma unroll
    for (int c = 0; c < 5; ++c) ssum += expf(acc[c] - m);
    ssum += __shfl_xor(ssum, 1);
    ssum += __shfl_xor(ssum, 2);
    ssum += __shfl_xor(ssum, 4);
    float lse = m + logf(ssum);
    float* orow = out + (size_t)node * NCLASS;
#pragma unroll
    for (int c = 0; c < 5; ++c) orow[ol + 8 * c] = acc[c] - lse;
}

extern "C" void kernel_launch(void* const* d_in, const int* in_sizes, int n_in,
                              void* d_out, int out_size, void* d_ws, size_t ws_size,
                              hipStream_t stream) {
    const float* x    = (const float*)d_in[0];
    const int*   ei   = (const int*)d_in[1];
    const float* W1   = (const float*)d_in[2];
    const float* b1   = (const float*)d_in[3];
    const float* W2   = (const float*)d_in[4];
    const float* b2   = (const float*)d_in[5];
    const float* attl = (const float*)d_in[6];
    const float* attr = (const float*)d_in[7];
    const int N = in_sizes[0] / FEAT;
    const int E = in_sizes[1] / 2;
    float* out = (float*)d_out;

    char* p = (char*)d_ws;
    auto take = [&](size_t bytes) {
        void* q = (void*)p;
        p += (bytes + 255) & ~(size_t)255;
        return q;
    };
    float*    h0   = (float*)take((size_t)N * HIDDEN * 4);  // = raw
    float*    h1   = (float*)take((size_t)N * HIDDEN * 4);
    float*    h2   = (float*)take((size_t)N * HIDDEN * 4);
    unsigned* hb0  = (unsigned*)take((size_t)N * 64 * 4);
    unsigned* hb1  = (unsigned*)take((size_t)N * 64 * 4);
    int*      deg  = (int*)take((size_t)N * 4);
    float*    dis  = (float*)take((size_t)N * 4);
    int*      offs = (int*)take((size_t)(N + 1) * 4);
    unsigned* partial = (unsigned*)take((size_t)NB * PITCH * 4);
    ushort*   lrank   = (ushort*)take((size_t)E * 2);
    int*      csrc = (int*)take((size_t)E * 4);
    float2*   al2A = (float2*)take((size_t)N * 8);
    float2*   al2B = (float2*)take((size_t)N * 8);
    float*    arA  = (float*)take((size_t)N * 4);
    float*    arB  = (float*)take((size_t)N * 4);
    int*      part = (int*)take(1024);

    // coef/selfc alias the 'partial' buffer (12.8 MB; dead after CSR build).
    float*    coef  = (float*)partial;
    float*    selfc = coef + E;

    const int nbl = (N + 255) / 256;
    const int CE = (E + NB - 1) / NB;

    k_hist<<<NB, 256, 0, stream>>>(ei, E, CE, partial, lrank);
    k_hscan<<<(PITCH + 255) / 256, 256, 0, stream>>>(partial, deg, N);
    k_dis<<<nbl, 256, 0, stream>>>(deg, dis, N);
    k_scan1<<<nbl, 256, 0, stream>>>(deg, offs, part, N);
    k_scan2<<<1, 256, 0, stream>>>(part, nbl);
    k_scan3<<<nbl, 256, 0, stream>>>(offs, part, N, E);
    k_csr_fill<<<NB, 256, 0, stream>>>(ei, E, CE, offs, partial, lrank, csrc);

    k_gemm1<<<(N + BM1 - 1) / BM1, 256, 0, stream>>>(x, W1, b1, h0, N);
    k_prep<<<(N + 3) / 4, 256, 0, stream>>>(h0, hb0, attl, attr, dis, al2A, arA, N);

    float*    fout[4] = {h1, h2, h1, h2};
    unsigned* hbin = hb0, *hbout = hb1;
    float2*   alin = al2A, *alout = al2B;
    float*    arin = arA,  *arout = arB;
    for (int l = 0; l < 4; ++l) {
        const float* attl_n = (l < 3) ? (attl + (l + 1) * HIDDEN) : nullptr;
        const float* attr_n = (l < 3) ? (attr + (l + 1) * HIDDEN) : nullptr;
        unsigned* hbo = (l < 3) ? hbout : nullptr;
        k_coef<<<(N + 3) / 4, 256, 0, stream>>>(alin, arin, offs, csrc, coef, selfc, N);
        k_aggregate<<<(N + 3) / 4, 256, 0, stream>>>(hbin, h0, coef, selfc, dis, offs, csrc,
                                                     fout[l], hbo, attl_n, attr_n,
                                                     alout, arout, N);
        unsigned* tb = hbin; hbin = hbout; hbout = tb;
        float2* ta = alin; alin = alout; alout = ta;
        float* tr = arin; arin = arout; arout = tr;
    }

    k_out<<<(N + 31) / 32, 256, 0, stream>>>(h2, W2, b2, out, N);
}

// Round 4
// 523.007 us; speedup vs baseline: 1.1604x; 1.1167x over previous
//
#include <hip/hip_runtime.h>
#include <cmath>

// FAGCN: N=50000, E=1.6M, FEAT=512, HIDDEN=128, CLASS=40, 4 layers, eps=0.3
// R13: coef fused back into k_aggregate, amortized — phase-1 computes 64 coefs
// per pass (csrc load -> al2 gather -> tanh, one per lane), hot loop pulls
// src/coef via __shfl from registers. Deletes k_coef (4 launches, ~40us) and
// the 12.8MB/layer coef round-trip while keeping R12's lean hot loop (tanh
// once per 64 edges, not per 16). Tails zero-padded in phase 1. k_dis merged
// into k_hscan. R12 counters: agg 63.5us VALU 47% occ 67%; k_coef ~10us/layer
// overhead made the split net-negative vs fusion.

#define HIDDEN 128
#define FEAT 512
#define NCLASS 40
#define LDST 40    // GEMM LDS row stride in ushorts (80 B)
#define LDSW 132   // k_out ws row stride in floats (528 B -> 4-bank shift/row)
#define NB 256     // histogram chunks (= blocks)
#define PITCH 12544  // words per partial row: 4 nodes/word -> supports N<=50176
#define BM1 64     // k_gemm1 M-tile

typedef __attribute__((ext_vector_type(8))) short short8;
typedef __attribute__((ext_vector_type(4))) float f32x4;

__device__ __forceinline__ float bf_lo(unsigned u) { return __uint_as_float(u << 16); }
__device__ __forceinline__ float bf_hi(unsigned u) { return __uint_as_float(u & 0xffff0000u); }
__device__ __forceinline__ unsigned pack_bf16(float x, float y) {
    unsigned ux = __float_as_uint(x);
    unsigned uy = __float_as_uint(y);
    unsigned lx = (ux + 0x7fffu + ((ux >> 16) & 1u)) >> 16;
    unsigned hy = (uy + 0x7fffu + ((uy >> 16) & 1u)) & 0xffff0000u;
    return hy | lx;
}
__device__ __forceinline__ float fast_tanh(float x) {
    x = fminf(fmaxf(x, -15.f), 15.f);
    float e = __expf(2.f * x);
    return (e - 1.f) / (e + 1.f);
}

// ---------------- per-chunk LDS histogram (8-bit packed) + local rank ----------
__global__ __launch_bounds__(256) void k_hist(const int* __restrict__ ei, int E, int CE,
                                              unsigned* __restrict__ partial,
                                              ushort* __restrict__ lrank) {
    __shared__ unsigned lh[PITCH];
    const int b = blockIdx.x, tid = threadIdx.x;
    for (int w = tid; w < PITCH; w += 256) lh[w] = 0;
    __syncthreads();
    int e0 = b * CE, e1 = min(E, e0 + CE);
    for (int e = e0 + tid; e < e1; e += 256) {
        int dst = ei[E + e];
        int sh = (dst & 3) * 8;
        unsigned old = atomicAdd(&lh[dst >> 2], 1u << sh);
        lrank[e] = (ushort)((old >> sh) & 0xffu);
    }
    __syncthreads();
    unsigned* prow = partial + (size_t)b * PITCH;
    for (int w = tid; w < PITCH; w += 256) prow[w] = lh[w];
}

// ---------------- cross-chunk exclusive scan (in place) + degree + dis ---------
__global__ __launch_bounds__(256) void k_hscan(unsigned* __restrict__ partial,
                                               int* __restrict__ deg,
                                               float* __restrict__ dis, int n) {
    int w = blockIdx.x * 256 + threadIdx.x;
    if (w >= PITCH) return;
    unsigned run = 0;
    size_t idx = w;
    for (int b = 0; b < NB; ++b, idx += PITCH) {
        unsigned v = partial[idx];
        partial[idx] = run;
        run += v;
    }
    int node = 4 * w;
    int d0 = run & 0xffu, d1 = (run >> 8) & 0xffu, d2 = (run >> 16) & 0xffu, d3 = run >> 24;
    if (node < n)     { deg[node]     = d0; dis[node]     = rsqrtf((float)(d0 + 1)); }
    if (node + 1 < n) { deg[node + 1] = d1; dis[node + 1] = rsqrtf((float)(d1 + 1)); }
    if (node + 2 < n) { deg[node + 2] = d2; dis[node + 2] = rsqrtf((float)(d2 + 1)); }
    if (node + 3 < n) { deg[node + 3] = d3; dis[node + 3] = rsqrtf((float)(d3 + 1)); }
}

// ---------------- exclusive scan over node degrees (offs) ----------------
__global__ __launch_bounds__(256) void k_scan1(const int* __restrict__ deg, int* __restrict__ offs,
                                               int* __restrict__ part, int n) {
    __shared__ int s[256];
    int tid = threadIdx.x;
    int gid = blockIdx.x * 256 + tid;
    int v = (gid < n) ? deg[gid] : 0;
    s[tid] = v;
    __syncthreads();
    for (int off = 1; off < 256; off <<= 1) {
        int t = (tid >= off) ? s[tid - off] : 0;
        __syncthreads();
        s[tid] += t;
        __syncthreads();
    }
    if (gid < n) offs[gid] = s[tid] - v;
    if (tid == 255) part[blockIdx.x] = s[255];
}

__global__ __launch_bounds__(256) void k_scan2(int* __restrict__ part, int nb) {
    __shared__ int s[256];
    int tid = threadIdx.x;
    int v = (tid < nb) ? part[tid] : 0;
    s[tid] = v;
    __syncthreads();
    for (int off = 1; off < 256; off <<= 1) {
        int t = (tid >= off) ? s[tid - off] : 0;
        __syncthreads();
        s[tid] += t;
        __syncthreads();
    }
    if (tid < nb) part[tid] = s[tid] - v;
}

__global__ __launch_bounds__(256) void k_scan3(int* __restrict__ offs, const int* __restrict__ part,
                                               int n, int E) {
    int gid = blockIdx.x * 256 + threadIdx.x;
    if (gid < n) offs[gid] += part[blockIdx.x];
    if (gid == 0) offs[n] = E;
}

// ---------------- CSR fill: no atomics; chunk base row staged in LDS -----------
__global__ __launch_bounds__(256) void k_csr_fill(const int* __restrict__ ei, int E, int CE,
                                                  const int* __restrict__ offs,
                                                  const unsigned* __restrict__ partial,
                                                  const ushort* __restrict__ lrank,
                                                  int* __restrict__ csrc) {
    __shared__ unsigned lp[PITCH];
    const int b = blockIdx.x, tid = threadIdx.x;
    const unsigned* prow = partial + (size_t)b * PITCH;
    for (int w = tid; w < PITCH; w += 256) lp[w] = prow[w];
    __syncthreads();
    int e0 = b * CE, e1 = min(E, e0 + CE);
    for (int e = e0 + tid; e < e1; e += 256) {
        int dst = ei[E + e];
        int src = ei[e];
        unsigned wv = lp[dst >> 2];
        int base = (wv >> ((dst & 3) * 8)) & 0xffu;
        csrc[offs[dst] + base + (int)lrank[e]] = src;
    }
}

// ---------------- GEMM1: h = relu(x @ W1^T + b1), MFMA bf16 -------------------
__global__ __launch_bounds__(256) void k_gemm1(const float* __restrict__ x,
                                               const float* __restrict__ W1,
                                               const float* __restrict__ b1,
                                               float* __restrict__ h, int M) {
    __shared__ ushort As[BM1 * LDST];
    __shared__ ushort Bs[128 * LDST];
    const int tid = threadIdx.x;
    const int bm = blockIdx.x * BM1;
    const int wave = tid >> 6, lane = tid & 63;
    const int rh = (wave >> 1) * 32;   // wave row offset: 0 / 32
    const int ch = (wave & 1) * 64;    // wave col offset: 0 / 64
    const int sub = lane & 15, quad = lane >> 4;
    const int lrow = tid >> 3;         // 0..31
    const int lcol = (tid & 7) * 4;    // 0..28
    f32x4 acc[2][4] = {};
    float4 av[2], bv[4];
    // prologue: load K-tile 0 into registers
#pragma unroll
    for (int i = 0; i < 2; ++i) {
        int grow = bm + lrow + 32 * i;
        av[i] = (grow < M) ? *(const float4*)(x + (size_t)grow * FEAT + lcol)
                           : make_float4(0.f, 0.f, 0.f, 0.f);
    }
#pragma unroll
    for (int i = 0; i < 4; ++i)
        bv[i] = *(const float4*)(W1 + (size_t)(lrow + 32 * i) * FEAT + lcol);

    for (int k0 = 0; k0 < FEAT; k0 += 32) {
        // stage current tile regs -> LDS (bf16 pack)
#pragma unroll
        for (int i = 0; i < 2; ++i)
            *(uint2*)(As + (lrow + 32 * i) * LDST + lcol) =
                make_uint2(pack_bf16(av[i].x, av[i].y), pack_bf16(av[i].z, av[i].w));
#pragma unroll
        for (int i = 0; i < 4; ++i)
            *(uint2*)(Bs + (lrow + 32 * i) * LDST + lcol) =
                make_uint2(pack_bf16(bv[i].x, bv[i].y), pack_bf16(bv[i].z, bv[i].w));
        __syncthreads();
        // prefetch next K-tile into registers (overlaps ds_read + MFMA below)
        if (k0 + 32 < FEAT) {
            const int kn = k0 + 32;
#pragma unroll
            for (int i = 0; i < 2; ++i) {
                int grow = bm + lrow + 32 * i;
                av[i] = (grow < M) ? *(const float4*)(x + (size_t)grow * FEAT + kn + lcol)
                                   : make_float4(0.f, 0.f, 0.f, 0.f);
            }
#pragma unroll
            for (int i = 0; i < 4; ++i)
                bv[i] = *(const float4*)(W1 + (size_t)(lrow + 32 * i) * FEAT + kn + lcol);
        }
        short8 af[2], bfr[4];
#pragma unroll
        for (int t = 0; t < 2; ++t)
            af[t] = *(const short8*)(As + (rh + t * 16 + sub) * LDST + quad * 8);
#pragma unroll
        for (int u = 0; u < 4; ++u)
            bfr[u] = *(const short8*)(Bs + (ch + u * 16 + sub) * LDST + quad * 8);
#pragma unroll
        for (int t = 0; t < 2; ++t)
#pragma unroll
            for (int u = 0; u < 4; ++u)
                acc[t][u] = __builtin_amdgcn_mfma_f32_16x16x32_bf16(af[t], bfr[u], acc[t][u], 0, 0, 0);
        __syncthreads();
    }
    float b1v[4];
#pragma unroll
    for (int u = 0; u < 4; ++u) b1v[u] = b1[ch + u * 16 + sub];
#pragma unroll
    for (int t = 0; t < 2; ++t) {
#pragma unroll
        for (int u = 0; u < 4; ++u) {
            int col = ch + u * 16 + sub;
#pragma unroll
            for (int r2 = 0; r2 < 4; ++r2) {
                int grow = bm + rh + t * 16 + quad * 4 + r2;
                if (grow < M)
                    h[(size_t)grow * HIDDEN + col] = fmaxf(acc[t][u][r2] + b1v[u], 0.f);
            }
        }
    }
}

// ---------------- prep: bf16 pack + layer-0 dots -> {al,dis}, ar ----------------
__global__ __launch_bounds__(256) void k_prep(const float* __restrict__ h, unsigned* __restrict__ hbf,
                       const float* __restrict__ attl, const float* __restrict__ attr,
                       const float* __restrict__ dis, float2* __restrict__ al2,
                       float* __restrict__ ar, int n) {
    int node = (blockIdx.x * blockDim.x + threadIdx.x) >> 6;
    int lane = threadIdx.x & 63;
    if (node >= n) return;
    float2 hv = ((const float2*)(h + (size_t)node * HIDDEN))[lane];
    hbf[(size_t)node * 64 + lane] = pack_bf16(hv.x, hv.y);
    float pl = hv.x * attl[2 * lane] + hv.y * attl[2 * lane + 1];
    float pr = hv.x * attr[2 * lane] + hv.y * attr[2 * lane + 1];
    for (int off = 32; off; off >>= 1) {
        pl += __shfl_down(pl, off);
        pr += __shfl_down(pr, off);
    }
    if (lane == 0) {
        al2[node] = make_float2(pl, dis[node]);
        ar[node] = pr;
    }
}

// ---------------- aggregate: phase-1 coef batch (64/pass) + shfl distribution ---
// Per 64-edge chunk: all lanes compute one coef (csrc -> al2 gather -> tanh),
// then the 16-edge hot loop pulls src/coef via __shfl. Tanh cost amortized
// 1/64 edges; tails zero-padded (cmy=0, smy=node) so the 4-edge body covers
// leftovers with no special casing.
__global__ __launch_bounds__(256) void k_aggregate(
                            const unsigned* __restrict__ hbf, const float* __restrict__ raw,
                            const float2* __restrict__ al2, const float* __restrict__ ar,
                            const int* __restrict__ offs, const int* __restrict__ csrc,
                            float* __restrict__ hout, unsigned* __restrict__ houtbf,
                            const float* __restrict__ attl_n, const float* __restrict__ attr_n,
                            float2* __restrict__ al2_o, float* __restrict__ ar_o, int n) {
    int node = (blockIdx.x * blockDim.x + threadIdx.x) >> 6;
    int lane = threadIdx.x & 63;
    if (node >= n) return;
    const int grp = lane >> 4;
    const int sub = lane & 15;
    const float arn = ar[node];
    const float2 selfld = al2[node];
    const float disn = selfld.y;
    float acc[8] = {0.f, 0.f, 0.f, 0.f, 0.f, 0.f, 0.f, 0.f};
    int e0 = offs[node], e1 = offs[node + 1];
    for (int base = e0; base < e1; base += 64) {
        int cnt = min(64, e1 - base);
        // phase 1: one coef per lane (zero-padded past cnt)
        int idx = base + lane;
        int smy = (lane < cnt) ? csrc[idx] : node;
        float2 lmy = al2[smy];
        float cmy = (lane < cnt) ? fast_tanh(lmy.x + arn) * lmy.y * disn : 0.f;
        // phase 2: 16-edge hot loop, src/coef via shfl
        int t = 0;
        for (; t + 16 <= cnt; t += 16) {
            int sa = __shfl(smy, t + grp);
            int sb = __shfl(smy, t + 4 + grp);
            int sc = __shfl(smy, t + 8 + grp);
            int sd = __shfl(smy, t + 12 + grp);
            float ca = __shfl(cmy, t + grp);
            float cb = __shfl(cmy, t + 4 + grp);
            float cc = __shfl(cmy, t + 8 + grp);
            float cd = __shfl(cmy, t + 12 + grp);
            uint4 ra = *(const uint4*)(hbf + (size_t)sa * 64 + sub * 4);
            uint4 rb = *(const uint4*)(hbf + (size_t)sb * 64 + sub * 4);
            uint4 rc = *(const uint4*)(hbf + (size_t)sc * 64 + sub * 4);
            uint4 rd = *(const uint4*)(hbf + (size_t)sd * 64 + sub * 4);
            acc[0] += ca * bf_lo(ra.x); acc[1] += ca * bf_hi(ra.x);
            acc[2] += ca * bf_lo(ra.y); acc[3] += ca * bf_hi(ra.y);
            acc[4] += ca * bf_lo(ra.z); acc[5] += ca * bf_hi(ra.z);
            acc[6] += ca * bf_lo(ra.w); acc[7] += ca * bf_hi(ra.w);
            acc[0] += cb * bf_lo(rb.x); acc[1] += cb * bf_hi(rb.x);
            acc[2] += cb * bf_lo(rb.y); acc[3] += cb * bf_hi(rb.y);
            acc[4] += cb * bf_lo(rb.z); acc[5] += cb * bf_hi(rb.z);
            acc[6] += cb * bf_lo(rb.w); acc[7] += cb * bf_hi(rb.w);
            acc[0] += cc * bf_lo(rc.x); acc[1] += cc * bf_hi(rc.x);
            acc[2] += cc * bf_lo(rc.y); acc[3] += cc * bf_hi(rc.y);
            acc[4] += cc * bf_lo(rc.z); acc[5] += cc * bf_hi(rc.z);
            acc[6] += cc * bf_lo(rc.w); acc[7] += cc * bf_hi(rc.w);
            acc[0] += cd * bf_lo(rd.x); acc[1] += cd * bf_hi(rd.x);
            acc[2] += cd * bf_lo(rd.y); acc[3] += cd * bf_hi(rd.y);
            acc[4] += cd * bf_lo(rd.z); acc[5] += cd * bf_hi(rd.z);
            acc[6] += cd * bf_lo(rd.w); acc[7] += cd * bf_hi(rd.w);
        }
        for (; t < cnt; t += 4) {   // zero-padded tail (covers 1-3 leftovers too)
            int sa = __shfl(smy, t + grp);
            float ca = __shfl(cmy, t + grp);
            uint4 ra = *(const uint4*)(hbf + (size_t)sa * 64 + sub * 4);
            acc[0] += ca * bf_lo(ra.x); acc[1] += ca * bf_hi(ra.x);
            acc[2] += ca * bf_lo(ra.y); acc[3] += ca * bf_hi(ra.y);
            acc[4] += ca * bf_lo(ra.z); acc[5] += ca * bf_hi(ra.z);
            acc[6] += ca * bf_lo(ra.w); acc[7] += ca * bf_hi(ra.w);
        }
    }
#pragma unroll
    for (int j = 0; j < 8; ++j) {
        acc[j] += __shfl_xor(acc[j], 16);
        acc[j] += __shfl_xor(acc[j], 32);
    }
    {   // self-loop term (post-reduce, replicated across groups)
        float c = fast_tanh(selfld.x + arn) * disn * disn;
        uint4 r = *(const uint4*)(hbf + (size_t)node * 64 + sub * 4);
        acc[0] += c * bf_lo(r.x); acc[1] += c * bf_hi(r.x);
        acc[2] += c * bf_lo(r.y); acc[3] += c * bf_hi(r.y);
        acc[4] += c * bf_lo(r.z); acc[5] += c * bf_hi(r.z);
        acc[6] += c * bf_lo(r.w); acc[7] += c * bf_hi(r.w);
    }
    float o[8];
    {
        float4 rv0 = *(const float4*)(raw + (size_t)node * HIDDEN + sub * 8);
        float4 rv1 = *(const float4*)(raw + (size_t)node * HIDDEN + sub * 8 + 4);
        o[0] = acc[0] + 0.3f * rv0.x; o[1] = acc[1] + 0.3f * rv0.y;
        o[2] = acc[2] + 0.3f * rv0.z; o[3] = acc[3] + 0.3f * rv0.w;
        o[4] = acc[4] + 0.3f * rv1.x; o[5] = acc[5] + 0.3f * rv1.y;
        o[6] = acc[6] + 0.3f * rv1.z; o[7] = acc[7] + 0.3f * rv1.w;
    }
    if (grp == 0) {
        *(float4*)(hout + (size_t)node * HIDDEN + sub * 8) = make_float4(o[0], o[1], o[2], o[3]);
        *(float4*)(hout + (size_t)node * HIDDEN + sub * 8 + 4) = make_float4(o[4], o[5], o[6], o[7]);
        if (houtbf) {
            uint4 pk = make_uint4(pack_bf16(o[0], o[1]), pack_bf16(o[2], o[3]),
                                  pack_bf16(o[4], o[5]), pack_bf16(o[6], o[7]));
            *(uint4*)(houtbf + (size_t)node * 64 + sub * 4) = pk;
        }
    }
    if (attl_n) {
        float4 a0 = *(const float4*)(attl_n + sub * 8);
        float4 a1 = *(const float4*)(attl_n + sub * 8 + 4);
        float4 c0 = *(const float4*)(attr_n + sub * 8);
        float4 c1 = *(const float4*)(attr_n + sub * 8 + 4);
        float pl = o[0] * a0.x + o[1] * a0.y + o[2] * a0.z + o[3] * a0.w +
                   o[4] * a1.x + o[5] * a1.y + o[6] * a1.z + o[7] * a1.w;
        float pr = o[0] * c0.x + o[1] * c0.y + o[2] * c0.z + o[3] * c0.w +
                   o[4] * c1.x + o[5] * c1.y + o[6] * c1.z + o[7] * c1.w;
        for (int off = 8; off; off >>= 1) {
            pl += __shfl_xor(pl, off);
            pr += __shfl_xor(pr, off);
        }
        if (lane == 0) {
            al2_o[node] = make_float2(pl, disn);
            ar_o[node] = pr;
        }
    }
}

// ---------------- output: log_softmax(h @ W2^T + b2) ---------------------------
// 8 lanes/node; lane ol=tid&7 computes classes {ol, ol+8, ..., ol+32} (acc[5]).
// ws padded to LDSW=132 floats/row -> conflict-free ds_read_b128.
__global__ __launch_bounds__(256, 4) void k_out(const float* __restrict__ h,
                                                const float* __restrict__ W2,
                                                const float* __restrict__ b2,
                                                float* __restrict__ out, int n) {
    __shared__ float ws[NCLASS * LDSW];
    __shared__ float bs[NCLASS];
    const int tid = threadIdx.x;
    for (int i = tid; i < NCLASS * (HIDDEN / 4); i += 256) {
        int r = i >> 5;          // row (class), 32 float4 per row
        int c4 = i & 31;         // float4 index within row
        *(float4*)(ws + r * LDSW + c4 * 4) = ((const float4*)W2)[i];
    }
    if (tid < NCLASS) bs[tid] = b2[tid];
    __syncthreads();
    int node = blockIdx.x * 32 + (tid >> 3);
    const int ol = tid & 7;
    if (node >= n) return;
    const float* hr = h + (size_t)node * HIDDEN;
    float acc[5];
#pragma unroll
    for (int c = 0; c < 5; ++c) acc[c] = bs[ol + 8 * c];
#pragma unroll
    for (int k0 = 0; k0 < HIDDEN; k0 += 16) {
        float4 h0 = *(const float4*)(hr + k0);
        float4 h1 = *(const float4*)(hr + k0 + 4);
        float4 h2v = *(const float4*)(hr + k0 + 8);
        float4 h3 = *(const float4*)(hr + k0 + 12);
#pragma unroll
        for (int c = 0; c < 5; ++c) {
            const float* w = ws + (ol + 8 * c) * LDSW + k0;
            float4 w0 = *(const float4*)(w);
            float4 w1 = *(const float4*)(w + 4);
            float4 w2v = *(const float4*)(w + 8);
            float4 w3 = *(const float4*)(w + 12);
            acc[c] += h0.x * w0.x + h0.y * w0.y + h0.z * w0.z + h0.w * w0.w +
                      h1.x * w1.x + h1.y * w1.y + h1.z * w1.z + h1.w * w1.w +
                      h2v.x * w2v.x + h2v.y * w2v.y + h2v.z * w2v.z + h2v.w * w2v.w +
                      h3.x * w3.x + h3.y * w3.y + h3.z * w3.z + h3.w * w3.w;
        }
    }
    float m = acc[0];
#pragma unroll
    for (int c = 1; c < 5; ++c) m = fmaxf(m, acc[c]);
    m = fmaxf(m, __shfl_xor(m, 1));
    m = fmaxf(m, __shfl_xor(m, 2));
    m = fmaxf(m, __shfl_xor(m, 4));
    float ssum = 0.f;
#pragma unroll
    for (int c = 0; c < 5; ++c) ssum += expf(acc[c] - m);
    ssum += __shfl_xor(ssum, 1);
    ssum += __shfl_xor(ssum, 2);
    ssum += __shfl_xor(ssum, 4);
    float lse = m + logf(ssum);
    float* orow = out + (size_t)node * NCLASS;
#pragma unroll
    for (int c = 0; c < 5; ++c) orow[ol + 8 * c] = acc[c] - lse;
}

extern "C" void kernel_launch(void* const* d_in, const int* in_sizes, int n_in,
                              void* d_out, int out_size, void* d_ws, size_t ws_size,
                              hipStream_t stream) {
    const float* x    = (const float*)d_in[0];
    const int*   ei   = (const int*)d_in[1];
    const float* W1   = (const float*)d_in[2];
    const float* b1   = (const float*)d_in[3];
    const float* W2   = (const float*)d_in[4];
    const float* b2   = (const float*)d_in[5];
    const float* attl = (const float*)d_in[6];
    const float* attr = (const float*)d_in[7];
    const int N = in_sizes[0] / FEAT;
    const int E = in_sizes[1] / 2;
    float* out = (float*)d_out;

    char* p = (char*)d_ws;
    auto take = [&](size_t bytes) {
        void* q = (void*)p;
        p += (bytes + 255) & ~(size_t)255;
        return q;
    };
    float*    h0   = (float*)take((size_t)N * HIDDEN * 4);  // = raw
    float*    h1   = (float*)take((size_t)N * HIDDEN * 4);
    float*    h2   = (float*)take((size_t)N * HIDDEN * 4);
    unsigned* hb0  = (unsigned*)take((size_t)N * 64 * 4);
    unsigned* hb1  = (unsigned*)take((size_t)N * 64 * 4);
    int*      deg  = (int*)take((size_t)N * 4);
    float*    dis  = (float*)take((size_t)N * 4);
    int*      offs = (int*)take((size_t)(N + 1) * 4);
    unsigned* partial = (unsigned*)take((size_t)NB * PITCH * 4);
    ushort*   lrank   = (ushort*)take((size_t)E * 2);
    int*      csrc = (int*)take((size_t)E * 4);
    float2*   al2A = (float2*)take((size_t)N * 8);
    float2*   al2B = (float2*)take((size_t)N * 8);
    float*    arA  = (float*)take((size_t)N * 4);
    float*    arB  = (float*)take((size_t)N * 4);
    int*      part = (int*)take(1024);

    const int nbl = (N + 255) / 256;
    const int CE = (E + NB - 1) / NB;

    k_hist<<<NB, 256, 0, stream>>>(ei, E, CE, partial, lrank);
    k_hscan<<<(PITCH + 255) / 256, 256, 0, stream>>>(partial, deg, dis, N);
    k_scan1<<<nbl, 256, 0, stream>>>(deg, offs, part, N);
    k_scan2<<<1, 256, 0, stream>>>(part, nbl);
    k_scan3<<<nbl, 256, 0, stream>>>(offs, part, N, E);
    k_csr_fill<<<NB, 256, 0, stream>>>(ei, E, CE, offs, partial, lrank, csrc);

    k_gemm1<<<(N + BM1 - 1) / BM1, 256, 0, stream>>>(x, W1, b1, h0, N);
    k_prep<<<(N + 3) / 4, 256, 0, stream>>>(h0, hb0, attl, attr, dis, al2A, arA, N);

    float*    fout[4] = {h1, h2, h1, h2};
    unsigned* hbin = hb0, *hbout = hb1;
    float2*   alin = al2A, *alout = al2B;
    float*    arin = arA,  *arout = arB;
    for (int l = 0; l < 4; ++l) {
        const float* attl_n = (l < 3) ? (attl + (l + 1) * HIDDEN) : nullptr;
        const float* attr_n = (l < 3) ? (attr + (l + 1) * HIDDEN) : nullptr;
        unsigned* hbo = (l < 3) ? hbout : nullptr;
        k_aggregate<<<(N + 3) / 4, 256, 0, stream>>>(hbin, h0, alin, arin, offs, csrc,
                                                     fout[l], hbo, attl_n, attr_n,
                                                     alout, arout, N);
        unsigned* tb = hbin; hbin = hbout; hbout = tb;
        float2* ta = alin; alin = alout; alout = ta;
        float* tr = arin; arin = arout; arout = tr;
    }

    k_out<<<(N + 31) / 32, 256, 0, stream>>>(h2, W2, b2, out, N);
}